// Round 6
// baseline (197.214 us; speedup 1.0000x reference)
//
#include <hip/hip_runtime.h>
#include <math.h>

// Problem constants (match reference)
constexpr int Bn = 4, Cn = 12, Hn = 256, Wn = 256;
constexpr int HWn  = Hn * Wn;        // 65536
constexpr int NPIX = Bn * HWn;       // 262144
constexpr int NPLANE = Bn * Cn;      // 48 (b,c) planes
constexpr int NMASK = 2 * NPLANE;    // 96 masks (48 pred + 48 target)
constexpr int NJOB  = 2 * NMASK;     // 192 EDT jobs (edt(mask), edt(~mask))
constexpr float LARGEf = 1.0e6f;
constexpr unsigned short SENT = 65535;

// fgflags layout: [0..3] = pred fg bitmask per batch (bit c), [4..7] = tgt fg

// ---------------------------------------------------------------------------
// Kernel Z: zero the fg flag words
// ---------------------------------------------------------------------------
__global__ void zero_kernel(unsigned int* __restrict__ fgflags) {
    if (threadIdx.x < 8) fgflags[threadIdx.x] = 0u;
}

// ---------------------------------------------------------------------------
// Kernel A: per-pixel softmax -> bit-packed masks word (bits 0..11 pred>0.5,
// bits 12..23 target one-hot), err = (prob-onehot)^2 per channel, CE partial
// per block, fg flags via block-OR + atomicOr.
// ---------------------------------------------------------------------------
__global__ void masks_kernel(const float* __restrict__ pred,
                             const int* __restrict__ target,
                             unsigned int* __restrict__ maskw,
                             float* __restrict__ err,
                             unsigned int* __restrict__ fgflags,
                             double* __restrict__ cepart) {
    int pix = blockIdx.x * blockDim.x + threadIdx.x;   // grid = NPIX exactly
    int b = pix >> 16;            // / HW (each block lies within one b)
    int p = pix & (HWn - 1);
    float v[Cn];
    float mx = -3.4e38f;
#pragma unroll
    for (int c = 0; c < Cn; ++c) {
        v[c] = pred[(size_t)(b * Cn + c) * HWn + p];
        mx = fmaxf(mx, v[c]);
    }
    int t = target[pix];
    float raw_t = 0.f, s = 0.f;
#pragma unroll
    for (int c = 0; c < Cn; ++c) {
        if (c == t) raw_t = v[c];
        v[c] = expf(v[c] - mx);
        s += v[c];
    }
    unsigned word = 1u << (Cn + t);   // target one-hot bit
#pragma unroll
    for (int c = 0; c < Cn; ++c) {
        float prob = v[c] / s;
        int pb = (prob > 0.5f) ? 1 : 0;
        word |= (unsigned)pb << c;
        float oh = (c == t) ? 1.0f : 0.0f;
        float d = prob - oh;
        err[(size_t)(b * Cn + c) * HWn + p] = d * d;
    }
    maskw[pix] = word;
    float logp_t = raw_t - mx - logf(s);

    // fg bits: wave-level OR (no barrier), then one atomic per wave
    unsigned worw = word;
    for (int o = 32; o > 0; o >>= 1) worw |= __shfl_down(worw, o, 64);
    // CE: wave-level double sum
    double ced = (double)logp_t;
    for (int o = 32; o > 0; o >>= 1) ced += __shfl_down(ced, o, 64);
    int lane = threadIdx.x & 63, wv = threadIdx.x >> 6;
    if (lane == 0) {
        atomicOr(&fgflags[b], worw & 0xFFFu);
        atomicOr(&fgflags[4 + b], worw >> Cn);
        cepart[blockIdx.x * 4 + wv] = ced;
    }
}

__device__ __forceinline__ int mask_has_fg(const unsigned int* fgflags, int m) {
    int mm = (m < NPLANE) ? m : m - NPLANE;
    int b = mm / Cn, c = mm % Cn;
    unsigned fg = (m < NPLANE) ? fgflags[b] : fgflags[4 + b];
    return (fg >> c) & 1;
}

// ---------------------------------------------------------------------------
// Kernel C: segmented column pass from bit-packed masks. Block = (job jb,
// column-group of 64). 4 segments of 64 rows, one thread per (segment, col).
// Local fwd/bwd scans -> LDS u8 (255 = LARGE sentinel, local values <=63);
// combine via segment end-states (exact integer fp32, validated R3). Writes
// column distance g as u16 (<=255 finite, SENT = LARGE).
// ---------------------------------------------------------------------------
constexpr int SEG  = 4;
constexpr int SEGR = Hn / SEG;   // 64
constexpr int STRb = 68;         // LDS byte stride per thread (17 words, coprime banks)

__global__ void colpass_kernel(const unsigned int* __restrict__ maskw,
                               const unsigned int* __restrict__ fgflags,
                               unsigned short* __restrict__ gcol) {
    int blk = blockIdx.x;         // 0..767
    int jb = blk >> 2;            // job 0..191
    int cg = blk & 3;             // column group
    int m  = (jb < NMASK) ? jb : jb - NMASK;
    if (!mask_has_fg(fgflags, m)) return;   // plane never consumed
    int mm = (m < NPLANE) ? m : m - NPLANE;
    int b = mm / Cn, c = mm % Cn;
    unsigned bit = (m < NPLANE) ? (unsigned)c : (unsigned)(Cn + c);
    unsigned inv = (jb < NMASK) ? 1u : 0u;  // feature = !maskbit for edt(mask)
    int tid = threadIdx.x;
    int s  = tid >> 6;            // segment 0..3 (uniform per wave)
    int jl = tid & 63;
    int j  = cg * 64 + jl;
    int r0 = s * SEGR;
    const unsigned int* mp = maskw + (size_t)b * HWn;
    unsigned short* gp = gcol + (size_t)jb * HWn;

    __shared__ unsigned char ldsF[256 * STRb];
    __shared__ unsigned char ldsB[256 * STRb];
    __shared__ float eF[256], eB[256];

    unsigned b0 = 0, b1 = 0;
    float cd = LARGEf;
    for (int i = 0; i < SEGR; ++i) {
        unsigned w = mp[(r0 + i) * Wn + j];
        unsigned f = ((w >> bit) & 1u) ^ inv;
        if (i < 32) b0 |= f << i; else b1 |= f << (i - 32);
        cd = f ? 0.f : fminf(cd + 1.f, LARGEf);
        ldsF[tid * STRb + i] = (unsigned char)fminf(cd, 255.f);   // <=63 or 255
    }
    eF[tid] = cd;
    cd = LARGEf;
    for (int i = SEGR - 1; i >= 0; --i) {
        unsigned f = ((i < 32) ? (b0 >> i) : (b1 >> (i - 32))) & 1u;
        cd = f ? 0.f : fminf(cd + 1.f, LARGEf);
        ldsB[tid * STRb + i] = (unsigned char)fminf(cd, 255.f);
    }
    eB[tid] = cd;
    __syncthreads();
    float x = LARGEf;                         // fwd inflow to my segment
    for (int sp = 0; sp < s; ++sp)
        x = fminf(eF[sp * 64 + jl], fminf(x + (float)SEGR, LARGEf));
    float y = LARGEf;                         // bwd inflow from below
    for (int sp = SEG - 1; sp > s; --sp)
        y = fminf(eB[sp * 64 + jl], fminf(y + (float)SEGR, LARGEf));
#pragma unroll 8
    for (int i = 0; i < SEGR; ++i) {
        unsigned char uf = ldsF[tid * STRb + i];
        unsigned char ub = ldsB[tid * STRb + i];
        float lf = (uf == 255u) ? LARGEf : (float)uf;
        float lb = (ub == 255u) ? LARGEf : (float)ub;
        float f = fminf(lf, fminf(x + (float)(i + 1), LARGEf));
        float w = fminf(lb, fminf(y + (float)(SEGR - i), LARGEf));
        float g = fminf(f, w);
        gp[(r0 + i) * Wn + j] = (g >= LARGEf) ? SENT : (unsigned short)g;
    }
}

// ---------------------------------------------------------------------------
// Kernel D: row pass fused with loss accumulation. Outward scan, split per
// polarity, 256-elem X=fl(1e12) padding (unconditional loads; padded
// candidates can never lower the min -> exact). 2-wide unrolled break check:
// extra candidates past the exit are genuine candidates (exact). Epilogue is
// a per-wave __shfl_down f64 reduction -> NO post-scan barriers; each wave
// writes one partial and retires independently (fixes R5's regression).
// ---------------------------------------------------------------------------
constexpr int RPAD = 256;

__device__ __forceinline__ float outward_min(const float* __restrict__ r,
                                             int j, float m0) {
    const float* pl = r + RPAD + j;
    float k2 = 1.f;                    // k^2
    for (int k = 1; k < Wn; k += 2) {
        if (k2 >= m0) break;
        float k2b = k2 + (float)(2 * k + 1);   // (k+1)^2
        m0 = fminf(m0, k2  + pl[-k]);
        m0 = fminf(m0, k2  + pl[k]);
        m0 = fminf(m0, k2b + pl[-k - 1]);
        m0 = fminf(m0, k2b + pl[k + 1]);
        k2 = k2b + (float)(2 * k + 3);         // (k+2)^2
    }
    return m0;
}

__global__ void rowpass_kernel(const unsigned short* __restrict__ gcol,
                               const float* __restrict__ err,
                               const unsigned int* __restrict__ fgflags,
                               double* __restrict__ partials) {
    int blk = blockIdx.x;             // 0 .. NMASK*Hn-1
    int m = blk >> 8;                 // mask plane 0..95
    int i = blk & (Hn - 1);           // row
    int j = threadIdx.x;              // col
    if (!mask_has_fg(fgflags, m)) {
        if (j < 4) partials[blk * 4 + j] = 0.0;   // plane zeroed by loss gating
        return;
    }
    const float X = 1e12f;            // == fl(1e6f*1e6f)
    __shared__ float rA[Wn + 2 * RPAD];
    __shared__ float rB[Wn + 2 * RPAD];
    const unsigned short* rp = gcol + (size_t)m * HWn + i * Wn;            // edt(mask)
    const unsigned short* rq = gcol + (size_t)(m + NMASK) * HWn + i * Wn;  // edt(~mask)
    unsigned short ua = rp[j], ub = rq[j];
    float a  = (ua == SENT) ? X : (float)((int)ua * (int)ua);
    float bb = (ub == SENT) ? X : (float)((int)ub * (int)ub);
    rA[j] = X; rA[RPAD + Wn + j] = X; rA[RPAD + j] = a;
    rB[j] = X; rB[RPAD + Wn + j] = X; rB[RPAD + j] = bb;
    __syncthreads();                  // the ONLY barrier in this kernel
    float m0 = outward_min(rA, j, a);
    float m1 = outward_min(rB, j, bb);
    float f = sqrtf(m0) + sqrtf(m1);  // field value at (m, i, j)
    int ep = (m < NPLANE) ? m : m - NPLANE;
    float e = err[(size_t)ep * HWn + i * Wn + j];
    double v = (double)(e * (f * f));
    for (int o = 32; o > 0; o >>= 1) v += __shfl_down(v, o, 64);
    if ((j & 63) == 0) partials[blk * 4 + (j >> 6)] = v;
}

// ---------------------------------------------------------------------------
// Kernel F: final reduction -> scalar (1024 threads)
// ---------------------------------------------------------------------------
__global__ void final_kernel(const double* __restrict__ partials,
                             const double* __restrict__ cepart,
                             float* __restrict__ out) {
    int tid = threadIdx.x;
    double a = 0.0, ce = 0.0;
    for (int idx = tid; idx < NMASK * Hn * 4; idx += 1024) a += partials[idx];
    for (int idx = tid; idx < 4096; idx += 1024) ce += cepart[idx];
    __shared__ double sa[1024], sc[1024];
    sa[tid] = a; sc[tid] = ce;
    __syncthreads();
    for (int s = 512; s > 0; s >>= 1) {
        if (tid < s) { sa[tid] += sa[tid + s]; sc[tid] += sc[tid + s]; }
        __syncthreads();
    }
    if (tid == 0) {
        double loss_sum = sa[0] / (double)NPIX;        // sum_c mean_{b,h,w}
        double cem = -sc[0] / (double)NPIX;            // ce
        double res = loss_sum / (double)Cn / (double)Bn / 3.0 + cem;
        out[0] = (float)res;
    }
}

// ---------------------------------------------------------------------------
extern "C" void kernel_launch(void* const* d_in, const int* in_sizes, int n_in,
                              void* d_out, int out_size, void* d_ws, size_t ws_size,
                              hipStream_t stream) {
    const float* pred  = (const float*)d_in[0];
    const int* target  = (const int*)d_in[1];
    float* out = (float*)d_out;
    char* ws = (char*)d_ws;

    // workspace layout (~40 MB total)
    unsigned int* maskw = (unsigned int*)ws;                         // NPIX*4 = 1 MB
    size_t off = (size_t)NPIX * 4;
    float* err = (float*)(ws + off);                                 // 48*65536*4 = 12.6 MB
    off += (size_t)NPLANE * HWn * 4;
    unsigned short* gcol = (unsigned short*)(ws + off);              // 192*65536*2 = 25.2 MB
    off += (size_t)NJOB * HWn * 2;
    unsigned int* fgflags = (unsigned int*)(ws + off);               // 8 u32 (pad 512)
    off += 512;
    double* partials = (double*)(ws + off);                          // 98304*8 = 786 KB
    off += (size_t)NMASK * Hn * 4 * 8;
    double* cepart = (double*)(ws + off);                            // 4096*8

    zero_kernel<<<1, 64, 0, stream>>>(fgflags);
    masks_kernel<<<NPIX / 256, 256, 0, stream>>>(pred, target, maskw, err, fgflags, cepart);
    colpass_kernel<<<NJOB * SEG, 256, 0, stream>>>(maskw, fgflags, gcol);
    rowpass_kernel<<<NMASK * Hn, 256, 0, stream>>>(gcol, err, fgflags, partials);
    final_kernel<<<1, 1024, 0, stream>>>(partials, cepart, out);
}

// Round 7
// 103.229 us; speedup vs baseline: 1.9105x; 1.9105x over previous
//
#include <hip/hip_runtime.h>
#include <math.h>

// Problem constants (match reference)
constexpr int Bn = 4, Cn = 12, Hn = 256, Wn = 256;
constexpr int HWn  = Hn * Wn;        // 65536
constexpr int NPIX = Bn * HWn;       // 262144
constexpr int NPLANE = Bn * Cn;      // 48 (b,c) planes
constexpr int NMASK = 2 * NPLANE;    // 96 masks (48 pred + 48 target)
constexpr int NJOB  = 2 * NMASK;     // 192 EDT jobs (edt(mask), edt(~mask))
constexpr float LARGEf = 1.0e6f;
constexpr unsigned short SENT = 65535;

// fgflags layout: [0..3] = pred fg bitmask per batch (bit c), [4..7] = tgt fg

// ---------------------------------------------------------------------------
// Kernel A: per-pixel softmax -> bit-packed masks word (bits 0..11 pred>0.5,
// bits 12..23 target one-hot), err = (prob-onehot)^2 per channel, CE partial
// per wave, per-wave OR word plain-stored (NO atomics -> no contention).
// ---------------------------------------------------------------------------
__global__ void masks_kernel(const float* __restrict__ pred,
                             const int* __restrict__ target,
                             unsigned int* __restrict__ maskw,
                             float* __restrict__ err,
                             unsigned int* __restrict__ blockOr,
                             double* __restrict__ cepart) {
    int pix = blockIdx.x * blockDim.x + threadIdx.x;   // grid = NPIX exactly
    int b = pix >> 16;            // / HW (each block lies within one b)
    int p = pix & (HWn - 1);
    float v[Cn];
    float mx = -3.4e38f;
#pragma unroll
    for (int c = 0; c < Cn; ++c) {
        v[c] = pred[(size_t)(b * Cn + c) * HWn + p];
        mx = fmaxf(mx, v[c]);
    }
    int t = target[pix];
    float raw_t = 0.f, s = 0.f;
#pragma unroll
    for (int c = 0; c < Cn; ++c) {
        if (c == t) raw_t = v[c];
        v[c] = expf(v[c] - mx);
        s += v[c];
    }
    unsigned word = 1u << (Cn + t);   // target one-hot bit
#pragma unroll
    for (int c = 0; c < Cn; ++c) {
        float prob = v[c] / s;
        int pb = (prob > 0.5f) ? 1 : 0;
        word |= (unsigned)pb << c;
        float oh = (c == t) ? 1.0f : 0.0f;
        float d = prob - oh;
        err[(size_t)(b * Cn + c) * HWn + p] = d * d;
    }
    maskw[pix] = word;
    float logp_t = raw_t - mx - logf(s);

    // wave-level OR + CE sum (no barriers), one plain store per wave
    unsigned worw = word;
    for (int o = 32; o > 0; o >>= 1) worw |= __shfl_down(worw, o, 64);
    double ced = (double)logp_t;
    for (int o = 32; o > 0; o >>= 1) ced += __shfl_down(ced, o, 64);
    int lane = threadIdx.x & 63, wv = threadIdx.x >> 6;
    if (lane == 0) {
        blockOr[blockIdx.x * 4 + wv] = worw;   // plain store, zero contention
        cepart[blockIdx.x * 4 + wv] = ced;
    }
}

// ---------------------------------------------------------------------------
// Kernel B: reduce the 4096 per-wave OR words -> 8 fgflags words.
// One wave per batch b (words b*1024 .. b*1024+1023). No atomics.
// ---------------------------------------------------------------------------
__global__ void flags_reduce_kernel(const unsigned int* __restrict__ blockOr,
                                    unsigned int* __restrict__ fgflags) {
    int lane = threadIdx.x & 63;
    int b = threadIdx.x >> 6;     // wave -> batch (4 waves)
    unsigned acc = 0;
#pragma unroll
    for (int k = 0; k < 16; ++k) acc |= blockOr[b * 1024 + k * 64 + lane];
    for (int o = 32; o > 0; o >>= 1) acc |= __shfl_down(acc, o, 64);
    if (lane == 0) {
        fgflags[b] = acc & 0xFFFu;
        fgflags[4 + b] = acc >> Cn;
    }
}

__device__ __forceinline__ int mask_has_fg(const unsigned int* fgflags, int m) {
    int mm = (m < NPLANE) ? m : m - NPLANE;
    int b = mm / Cn, c = mm % Cn;
    unsigned fg = (m < NPLANE) ? fgflags[b] : fgflags[4 + b];
    return (fg >> c) & 1;
}

// ---------------------------------------------------------------------------
// Kernel C: segmented column pass from bit-packed masks. Block = (job jb,
// column-group of 64). 4 segments of 64 rows, one thread per (segment, col).
// Local fwd/bwd scans -> LDS u8 (255 = LARGE sentinel, local values <=63);
// combine via segment end-states (exact integer fp32, validated R3). Writes
// column distance g as u16 (<=255 finite, SENT = LARGE).
// ---------------------------------------------------------------------------
constexpr int SEG  = 4;
constexpr int SEGR = Hn / SEG;   // 64
constexpr int STRb = 68;         // LDS byte stride per thread (17 words, coprime banks)

__global__ void colpass_kernel(const unsigned int* __restrict__ maskw,
                               const unsigned int* __restrict__ fgflags,
                               unsigned short* __restrict__ gcol) {
    int blk = blockIdx.x;         // 0..767
    int jb = blk >> 2;            // job 0..191
    int cg = blk & 3;             // column group
    int m  = (jb < NMASK) ? jb : jb - NMASK;
    if (!mask_has_fg(fgflags, m)) return;   // plane never consumed
    int mm = (m < NPLANE) ? m : m - NPLANE;
    int b = mm / Cn, c = mm % Cn;
    unsigned bit = (m < NPLANE) ? (unsigned)c : (unsigned)(Cn + c);
    unsigned inv = (jb < NMASK) ? 1u : 0u;  // feature = !maskbit for edt(mask)
    int tid = threadIdx.x;
    int s  = tid >> 6;            // segment 0..3 (uniform per wave)
    int jl = tid & 63;
    int j  = cg * 64 + jl;
    int r0 = s * SEGR;
    const unsigned int* mp = maskw + (size_t)b * HWn;
    unsigned short* gp = gcol + (size_t)jb * HWn;

    __shared__ unsigned char ldsF[256 * STRb];
    __shared__ unsigned char ldsB[256 * STRb];
    __shared__ float eF[256], eB[256];

    unsigned b0 = 0, b1 = 0;
    float cd = LARGEf;
    for (int i = 0; i < SEGR; ++i) {
        unsigned w = mp[(r0 + i) * Wn + j];
        unsigned f = ((w >> bit) & 1u) ^ inv;
        if (i < 32) b0 |= f << i; else b1 |= f << (i - 32);
        cd = f ? 0.f : fminf(cd + 1.f, LARGEf);
        ldsF[tid * STRb + i] = (unsigned char)fminf(cd, 255.f);   // <=63 or 255
    }
    eF[tid] = cd;
    cd = LARGEf;
    for (int i = SEGR - 1; i >= 0; --i) {
        unsigned f = ((i < 32) ? (b0 >> i) : (b1 >> (i - 32))) & 1u;
        cd = f ? 0.f : fminf(cd + 1.f, LARGEf);
        ldsB[tid * STRb + i] = (unsigned char)fminf(cd, 255.f);
    }
    eB[tid] = cd;
    __syncthreads();
    float x = LARGEf;                         // fwd inflow to my segment
    for (int sp = 0; sp < s; ++sp)
        x = fminf(eF[sp * 64 + jl], fminf(x + (float)SEGR, LARGEf));
    float y = LARGEf;                         // bwd inflow from below
    for (int sp = SEG - 1; sp > s; --sp)
        y = fminf(eB[sp * 64 + jl], fminf(y + (float)SEGR, LARGEf));
#pragma unroll 8
    for (int i = 0; i < SEGR; ++i) {
        unsigned char uf = ldsF[tid * STRb + i];
        unsigned char ub = ldsB[tid * STRb + i];
        float lf = (uf == 255u) ? LARGEf : (float)uf;
        float lb = (ub == 255u) ? LARGEf : (float)ub;
        float f = fminf(lf, fminf(x + (float)(i + 1), LARGEf));
        float w = fminf(lb, fminf(y + (float)(SEGR - i), LARGEf));
        float g = fminf(f, w);
        gp[(r0 + i) * Wn + j] = (g >= LARGEf) ? SENT : (unsigned short)g;
    }
}

// ---------------------------------------------------------------------------
// Kernel D: row pass fused with loss accumulation. Outward scan, split per
// polarity, 256-elem X=fl(1e12) padding (unconditional loads; padded
// candidates can never lower the min -> exact). 2-wide unrolled break check.
// Epilogue: per-wave __shfl_down f64 reduction, no post-scan barriers.
// ---------------------------------------------------------------------------
constexpr int RPAD = 256;

__device__ __forceinline__ float outward_min(const float* __restrict__ r,
                                             int j, float m0) {
    const float* pl = r + RPAD + j;
    float k2 = 1.f;                    // k^2
    for (int k = 1; k < Wn; k += 2) {
        if (k2 >= m0) break;
        float k2b = k2 + (float)(2 * k + 1);   // (k+1)^2
        m0 = fminf(m0, k2  + pl[-k]);
        m0 = fminf(m0, k2  + pl[k]);
        m0 = fminf(m0, k2b + pl[-k - 1]);
        m0 = fminf(m0, k2b + pl[k + 1]);
        k2 = k2b + (float)(2 * k + 3);         // (k+2)^2
    }
    return m0;
}

__global__ void rowpass_kernel(const unsigned short* __restrict__ gcol,
                               const float* __restrict__ err,
                               const unsigned int* __restrict__ fgflags,
                               double* __restrict__ partials) {
    int blk = blockIdx.x;             // 0 .. NMASK*Hn-1
    int m = blk >> 8;                 // mask plane 0..95
    int i = blk & (Hn - 1);           // row
    int j = threadIdx.x;              // col
    if (!mask_has_fg(fgflags, m)) {
        if (j < 4) partials[blk * 4 + j] = 0.0;   // plane zeroed by loss gating
        return;
    }
    const float X = 1e12f;            // == fl(1e6f*1e6f)
    __shared__ float rA[Wn + 2 * RPAD];
    __shared__ float rB[Wn + 2 * RPAD];
    const unsigned short* rp = gcol + (size_t)m * HWn + i * Wn;            // edt(mask)
    const unsigned short* rq = gcol + (size_t)(m + NMASK) * HWn + i * Wn;  // edt(~mask)
    unsigned short ua = rp[j], ub = rq[j];
    float a  = (ua == SENT) ? X : (float)((int)ua * (int)ua);
    float bb = (ub == SENT) ? X : (float)((int)ub * (int)ub);
    rA[j] = X; rA[RPAD + Wn + j] = X; rA[RPAD + j] = a;
    rB[j] = X; rB[RPAD + Wn + j] = X; rB[RPAD + j] = bb;
    __syncthreads();                  // the ONLY barrier in this kernel
    float m0 = outward_min(rA, j, a);
    float m1 = outward_min(rB, j, bb);
    float f = sqrtf(m0) + sqrtf(m1);  // field value at (m, i, j)
    int ep = (m < NPLANE) ? m : m - NPLANE;
    float e = err[(size_t)ep * HWn + i * Wn + j];
    double v = (double)(e * (f * f));
    for (int o = 32; o > 0; o >>= 1) v += __shfl_down(v, o, 64);
    if ((j & 63) == 0) partials[blk * 4 + (j >> 6)] = v;
}

// ---------------------------------------------------------------------------
// Kernel F: final reduction -> scalar (1024 threads)
// ---------------------------------------------------------------------------
__global__ void final_kernel(const double* __restrict__ partials,
                             const double* __restrict__ cepart,
                             float* __restrict__ out) {
    int tid = threadIdx.x;
    double a = 0.0, ce = 0.0;
    for (int idx = tid; idx < NMASK * Hn * 4; idx += 1024) a += partials[idx];
    for (int idx = tid; idx < 4096; idx += 1024) ce += cepart[idx];
    __shared__ double sa[1024], sc[1024];
    sa[tid] = a; sc[tid] = ce;
    __syncthreads();
    for (int s = 512; s > 0; s >>= 1) {
        if (tid < s) { sa[tid] += sa[tid + s]; sc[tid] += sc[tid + s]; }
        __syncthreads();
    }
    if (tid == 0) {
        double loss_sum = sa[0] / (double)NPIX;        // sum_c mean_{b,h,w}
        double cem = -sc[0] / (double)NPIX;            // ce
        double res = loss_sum / (double)Cn / (double)Bn / 3.0 + cem;
        out[0] = (float)res;
    }
}

// ---------------------------------------------------------------------------
extern "C" void kernel_launch(void* const* d_in, const int* in_sizes, int n_in,
                              void* d_out, int out_size, void* d_ws, size_t ws_size,
                              hipStream_t stream) {
    const float* pred  = (const float*)d_in[0];
    const int* target  = (const int*)d_in[1];
    float* out = (float*)d_out;
    char* ws = (char*)d_ws;

    // workspace layout (~40 MB total)
    unsigned int* maskw = (unsigned int*)ws;                         // NPIX*4 = 1 MB
    size_t off = (size_t)NPIX * 4;
    float* err = (float*)(ws + off);                                 // 48*65536*4 = 12.6 MB
    off += (size_t)NPLANE * HWn * 4;
    unsigned short* gcol = (unsigned short*)(ws + off);              // 192*65536*2 = 25.2 MB
    off += (size_t)NJOB * HWn * 2;
    unsigned int* fgflags = (unsigned int*)(ws + off);               // 8 u32 (pad 512)
    off += 512;
    unsigned int* blockOr = (unsigned int*)(ws + off);               // 4096*4 = 16 KB
    off += 4096 * 4;
    double* partials = (double*)(ws + off);                          // 98304*8 = 786 KB
    off += (size_t)NMASK * Hn * 4 * 8;
    double* cepart = (double*)(ws + off);                            // 4096*8

    masks_kernel<<<NPIX / 256, 256, 0, stream>>>(pred, target, maskw, err, blockOr, cepart);
    flags_reduce_kernel<<<1, 256, 0, stream>>>(blockOr, fgflags);
    colpass_kernel<<<NJOB * SEG, 256, 0, stream>>>(maskw, fgflags, gcol);
    rowpass_kernel<<<NMASK * Hn, 256, 0, stream>>>(gcol, err, fgflags, partials);
    final_kernel<<<1, 1024, 0, stream>>>(partials, cepart, out);
}